// Round 1
// baseline (1520.398 us; speedup 1.0000x reference)
//
#include <hip/hip_runtime.h>
#include <math.h>

// Problem: B=8, H=8, S=4096, D=64. FACTOR=1 -> topk = S (full sort).
#define S 4096
#define HALF_S 2048
#define LOG2S 12
#define D 64
#define NT 256
#define BH 64  // B*H

__device__ __forceinline__ float2 cmul(float2 a, float2 b) {
    return make_float2(a.x * b.x - a.y * b.y, a.x * b.y + a.y * b.x);
}

// In-place radix-2 DIT forward FFT of length 4096 on LDS array z,
// twiddles tw[t] = exp(-2*pi*i*t/S), t in [0, 2048).
__device__ __forceinline__ void fft4096(float2* z, const float2* tw, int tid) {
    // bit-reverse permutation (12 bits); each pair touched by exactly one thread
    for (int i = tid; i < S; i += NT) {
        int r = (int)(__brev((unsigned)i) >> (32 - LOG2S));
        if (i < r) {
            float2 a = z[i], b = z[r];
            z[i] = b; z[r] = a;
        }
    }
    __syncthreads();
    int lh = 0;  // log2(half)
    for (int len = 2; len <= S; len <<= 1, ++lh) {
        const int half = len >> 1;
        const int tshift = LOG2S - lh - 1;  // twiddle stride = S/len as shift
        for (int p = tid; p < HALF_S; p += NT) {
            int pos = p & (half - 1);
            int i0 = ((p >> lh) << (lh + 1)) + pos;
            int i1 = i0 + half;
            float2 w = tw[pos << tshift];
            float2 a = z[i0], b = z[i1];
            float2 t = cmul(w, b);
            z[i0] = make_float2(a.x + t.x, a.y + t.y);
            z[i1] = make_float2(a.x - t.x, a.y - t.y);
        }
        __syncthreads();
    }
}

// One block per (bh, d) column. Computes circular corr via packed FFT,
// sorts descending, softmax, writes weights in [bh][d][i] layout.
__global__ __launch_bounds__(NT) void corr_sort_softmax_kernel(
    const float* __restrict__ q, const float* __restrict__ kk,
    float* __restrict__ wt) {
    __shared__ float lds[2 * S];    // 32 KB: float2 z[4096] view / float s[4096]
    __shared__ float2 tw[HALF_S];   // 16 KB twiddles
    __shared__ float red[NT / 64];
    float2* z = (float2*)lds;

    const int tid = threadIdx.x;
    const int col = blockIdx.x;
    const int bh = col >> 6;
    const int d = col & (D - 1);

    // twiddle table: exp(-2*pi*i*t/S)
    for (int t = tid; t < HALF_S; t += NT) {
        float sv, cv;
        sincospif(-2.0f * (float)t / (float)S, &sv, &cv);
        tw[t] = make_float2(cv, sv);
    }

    // load the two columns packed as z = q + i*k (strided global reads;
    // 64 blocks share each (b,h) slab via L2/L3)
    const size_t base = (size_t)bh * S * D + d;
    for (int t = tid; t < S; t += NT)
        z[t] = make_float2(q[base + (size_t)t * D], kk[base + (size_t)t * D]);
    __syncthreads();

    // forward FFT of packed signal
    fft4096(z, tw, tid);

    // spectral combine: Z = Q + i*K (Hermitian unpack), C = Q * conj(K).
    // Store conj(C) so a second FORWARD FFT gives conj(N * ifft(C)).
    for (int f = tid; f <= HALF_S; f += NT) {
        if (f == 0) {
            float2 Z0 = z[0];                      // Q0 + i*K0, both real
            z[0] = make_float2(Z0.x * Z0.y, 0.0f);
        } else if (f == HALF_S) {
            float2 Zh = z[HALF_S];                 // Qh + i*Kh, both real
            z[HALF_S] = make_float2(Zh.x * Zh.y, 0.0f);
        } else {
            float2 Zf = z[f], Zn = z[S - f];
            float2 Q = make_float2(0.5f * (Zf.x + Zn.x), 0.5f * (Zf.y - Zn.y));
            float2 K = make_float2(0.5f * (Zf.y + Zn.y), -0.5f * (Zf.x - Zn.x));
            // C = Q * conj(K)
            float2 C = make_float2(Q.x * K.x + Q.y * K.y, Q.y * K.x - Q.x * K.y);
            z[f] = make_float2(C.x, -C.y);         // conj(C[f])
            z[S - f] = C;                          // conj(C[S-f]) = C[f]
        }
    }
    __syncthreads();

    // inverse FFT via forward-on-conjugate; corr[t] = Re(...) / S
    fft4096(z, tw, tid);

    // extract real parts into a flat float array (aliases z; regs + barriers)
    float vals[S / NT];
#pragma unroll
    for (int i = 0; i < S / NT; ++i)
        vals[i] = z[tid + i * NT].x * (1.0f / (float)S);
    __syncthreads();
    float* s = lds;
#pragma unroll
    for (int i = 0; i < S / NT; ++i)
        s[tid + i * NT] = vals[i];
    __syncthreads();

    // bitonic sort, descending
    for (int k2 = 2; k2 <= S; k2 <<= 1) {
        for (int j = k2 >> 1; j > 0; j >>= 1) {
            for (int i = tid; i < S; i += NT) {
                int l = i ^ j;
                if (l > i) {
                    float a = s[i], b = s[l];
                    bool desc = ((i & k2) == 0);
                    if (desc ? (a < b) : (a > b)) { s[i] = b; s[l] = a; }
                }
            }
            __syncthreads();
        }
    }

    // softmax over sorted axis (max is s[0] after descending sort)
    const float m = s[0];
    float part = 0.0f;
    float ev[S / NT];
#pragma unroll
    for (int i = 0; i < S / NT; ++i) {
        ev[i] = __expf(s[tid + i * NT] - m);
        part += ev[i];
    }
#pragma unroll
    for (int off = 32; off > 0; off >>= 1) part += __shfl_down(part, off);
    if ((tid & 63) == 0) red[tid >> 6] = part;
    __syncthreads();
    const float total = red[0] + red[1] + red[2] + red[3];
    const float inv = 1.0f / total;

    float* wcol = wt + ((size_t)bh * D + d) * S;   // [bh][d][i] layout
#pragma unroll
    for (int i = 0; i < S / NT; ++i)
        wcol[tid + i * NT] = ev[i] * inv;
}

// out[bh][i][l] = sum_j wt[bh][j][i] * values[bh][j][l]  (j,l < 64)
// grid: BH * (S/64) blocks; each block does a 64-row i-tile.
__global__ __launch_bounds__(NT) void mix_kernel(
    const float* __restrict__ wt, const float* __restrict__ v,
    float* __restrict__ out) {
    __shared__ float V[D][D];
    __shared__ float W[D][D + 1];
    const int tid = threadIdx.x;
    const int bh = blockIdx.x >> 6;
    const int tile = blockIdx.x & 63;

    for (int idx = tid; idx < D * D; idx += NT) {
        int j = idx >> 6, l = idx & 63;
        V[j][l] = v[((size_t)bh * S + j) * D + l];
        W[j][l] = wt[((size_t)bh * D + j) * S + tile * D + l];
    }
    __syncthreads();

    const int l = tid & 63;
    const int ig = tid >> 6;  // 4 groups x 16 rows
    float acc[16];
#pragma unroll
    for (int ii = 0; ii < 16; ++ii) acc[ii] = 0.0f;
    for (int j = 0; j < D; ++j) {
        float vl = V[j][l];
#pragma unroll
        for (int ii = 0; ii < 16; ++ii)
            acc[ii] += W[j][ig * 16 + ii] * vl;
    }
#pragma unroll
    for (int ii = 0; ii < 16; ++ii)
        out[((size_t)bh * S + tile * D + ig * 16 + ii) * D + l] = acc[ii];
}

extern "C" void kernel_launch(void* const* d_in, const int* in_sizes, int n_in,
                              void* d_out, int out_size, void* d_ws, size_t ws_size,
                              hipStream_t stream) {
    const float* q = (const float*)d_in[0];
    const float* k = (const float*)d_in[1];
    const float* v = (const float*)d_in[2];
    float* out = (float*)d_out;
    float* wt = (float*)d_ws;  // needs BH*D*S*4 = 64 MB of workspace

    corr_sort_softmax_kernel<<<dim3(BH * D), dim3(NT), 0, stream>>>(q, k, wt);
    mix_kernel<<<dim3(BH * (S / D)), dim3(NT), 0, stream>>>(wt, v, out);
}

// Round 2
// 717.408 us; speedup vs baseline: 2.1193x; 2.1193x over previous
//
#include <hip/hip_runtime.h>
#include <math.h>

// B=8, H=8, S=4096, D=64. FACTOR=1 -> topk = S (full descending sort per column).
#define S 4096
#define HALF_S 2048
#define D 64
#define NT 256
#define BH 64
#define EPT 16

__device__ __forceinline__ float2 cadd(float2 a, float2 b) { return make_float2(a.x + b.x, a.y + b.y); }
__device__ __forceinline__ float2 csub(float2 a, float2 b) { return make_float2(a.x - b.x, a.y - b.y); }
__device__ __forceinline__ float2 cmul(float2 a, float2 b) {
    return make_float2(a.x * b.x - a.y * b.y, a.x * b.y + a.y * b.x);
}

// folded twiddle: table holds tw[t]=exp(-2*pi*i*t/4096) for t<1024;
// for idx in [1024,2048): tw[idx] = -i * tw[idx-1024]
__device__ __forceinline__ float2 twget(const float2* tw, int idx) {
    float2 w = tw[idx & 1023];
    if (idx & 1024) w = make_float2(w.y, -w.x);
    return w;
}

// compare-exchange with direction (desc=true keeps max in a)
#define CE(a, b, desc) { float _mn = fminf(a, b), _mx = fmaxf(a, b); \
                         (a) = (desc) ? _mx : _mn; (b) = (desc) ? _mn : _mx; }

__global__ __launch_bounds__(NT) void corr_sort_softmax_kernel(
    const float* __restrict__ q, const float* __restrict__ kk,
    float* __restrict__ wt)
{
    __shared__ float2 z[S];       // 32 KB; aliased as stride-17 sort buffer later
    __shared__ float2 tw[1024];   // 8 KB folded twiddles; aliased as reduce scratch
    const int tid = threadIdx.x;
    const int bh = blockIdx.x >> 6;
    const int d  = blockIdx.x & (D - 1);

    for (int t = tid; t < 1024; t += NT) {
        float sv, cv;
        sincospif(-(float)t * (1.0f / 2048.0f), &sv, &cv);
        tw[t] = make_float2(cv, sv);
    }

    // Global gather in BIT-REVERSED order (loads were uncoalesced anyway; this
    // makes the DIT FFT need no in-LDS bit-reverse pass). z = q + i*k packed.
    const size_t base = (size_t)bh * (S * D) + d;
#pragma unroll
    for (int m = 0; m < EPT; ++m) {
        int i = tid + NT * m;
        int r = (int)(__brev((unsigned)i) >> 20);   // 12-bit reversal
        float qa = __builtin_nontemporal_load(&q[base + (size_t)r * D]);
        float ka = __builtin_nontemporal_load(&kk[base + (size_t)r * D]);
        z[i] = make_float2(qa, ka);
    }
    __syncthreads();

    // Forward FFT: DIT, fused double radix-2 stages (radix-4), bit-reversed
    // input -> natural-order output.
    for (int lh = 0; lh <= 10; lh += 2) {
        const int h = 1 << lh;
#pragma unroll
        for (int pp = 0; pp < 4; ++pp) {
            int p = tid + NT * pp;
            int pos = p & (h - 1);
            int i0 = ((p >> lh) << (lh + 2)) + pos;
            float2 a0 = z[i0], a1 = z[i0 + h], a2 = z[i0 + 2 * h], a3 = z[i0 + 3 * h];
            float2 w1 = twget(tw, pos << (11 - lh));
            float2 t1 = cmul(w1, a1), t3 = cmul(w1, a3);
            float2 b0 = cadd(a0, t1), b1 = csub(a0, t1);
            float2 b2 = cadd(a2, t3), b3 = csub(a2, t3);
            float2 w2 = tw[pos << (10 - lh)];            // idx < 1024 always
            float2 w2m = make_float2(w2.y, -w2.x);        // -i * w2
            float2 u2 = cmul(w2, b2);
            float2 u3 = cmul(w2m, b3);
            z[i0]         = cadd(b0, u2);
            z[i0 + 2 * h] = csub(b0, u2);
            z[i0 + h]     = cadd(b1, u3);
            z[i0 + 3 * h] = csub(b1, u3);
        }
        __syncthreads();
    }

    // Spectral combine (natural order): unpack Q,K from packed transform,
    // C = Q * conj(K); store conj(C) so a FORWARD transform yields S*corr.
    for (int f = tid; f <= HALF_S; f += NT) {
        if (f == 0) {
            float2 Z0 = z[0];
            z[0] = make_float2(Z0.x * Z0.y, 0.0f);
        } else if (f == HALF_S) {
            float2 Zh = z[HALF_S];
            z[HALF_S] = make_float2(Zh.x * Zh.y, 0.0f);
        } else {
            float2 Zf = z[f], Zn = z[S - f];
            float2 Q = make_float2(0.5f * (Zf.x + Zn.x), 0.5f * (Zf.y - Zn.y));
            float2 K = make_float2(0.5f * (Zf.y + Zn.y), -0.5f * (Zf.x - Zn.x));
            float2 C = make_float2(Q.x * K.x + Q.y * K.y, Q.y * K.x - Q.x * K.y);
            z[f]     = make_float2(C.x, -C.y);
            z[S - f] = C;
        }
    }
    __syncthreads();

    // Inverse FFT via forward-DIF on conj(C): natural input -> bit-reversed
    // output. Scrambled order is fine: a full sort follows.
    for (int lh = 10; lh >= 0; lh -= 2) {
        const int h = 1 << lh;
#pragma unroll
        for (int pp = 0; pp < 4; ++pp) {
            int p = tid + NT * pp;
            int pos = p & (h - 1);
            int i0 = ((p >> lh) << (lh + 2)) + pos;
            float2 a0 = z[i0], a1 = z[i0 + h], a2 = z[i0 + 2 * h], a3 = z[i0 + 3 * h];
            float2 w2 = tw[pos << (10 - lh)];
            float2 w2m = make_float2(w2.y, -w2.x);
            float2 c0 = cadd(a0, a2);
            float2 c2 = cmul(w2,  csub(a0, a2));
            float2 c1 = cadd(a1, a3);
            float2 c3 = cmul(w2m, csub(a1, a3));
            float2 w1 = twget(tw, pos << (11 - lh));
            z[i0]         = cadd(c0, c1);
            z[i0 + h]     = cmul(w1, csub(c0, c1));
            z[i0 + 2 * h] = cadd(c2, c3);
            z[i0 + 3 * h] = cmul(w1, csub(c2, c3));
        }
        __syncthreads();
    }

    // Extract corr values; move to per-thread registers (16 contiguous logical
    // slots/thread) through a stride-17 padded buffer (conflict-free).
    float e[EPT];
    {
        float vals[EPT];
#pragma unroll
        for (int m = 0; m < EPT; ++m)
            vals[m] = z[tid + NT * m].x * (1.0f / (float)S);
        __syncthreads();
        float* s17 = (float*)z;
#pragma unroll
        for (int m = 0; m < EPT; ++m) {
            int i = tid + NT * m;
            s17[17 * (i >> 4) + (i & 15)] = vals[m];
        }
        __syncthreads();
#pragma unroll
        for (int m = 0; m < EPT; ++m)
            e[m] = s17[17 * tid + m];
    }

    // ---- bitonic sort, descending; thread t owns logical elements 16t..16t+15
    // k = 2,4,8 : fully in-register, direction from element index
#pragma unroll
    for (int m = 0; m < 16; m += 2) CE(e[m], e[m + 1], ((m & 2) == 0));
#pragma unroll
    for (int j = 2; j >= 1; j >>= 1)
#pragma unroll
        for (int m = 0; m < 16; ++m)
            if ((m & j) == 0) CE(e[m], e[m | j], ((m & 4) == 0));
#pragma unroll
    for (int j = 4; j >= 1; j >>= 1)
#pragma unroll
        for (int m = 0; m < 16; ++m)
            if ((m & j) == 0) CE(e[m], e[m | j], ((m & 8) == 0));
    {   // k = 16 : in-register, direction uniform per thread
        const bool d16 = ((tid & 1) == 0);
#pragma unroll
        for (int j = 8; j >= 1; j >>= 1)
#pragma unroll
            for (int m = 0; m < 16; ++m)
                if ((m & j) == 0) CE(e[m], e[m | j], d16);
    }
    // k = 32..4096 : j>=16 via shuffle (mask<64) or LDS (mask 64/128), tail in regs
    {
        float* s17 = (float*)z;
        for (int k2 = 32; k2 <= S; k2 <<= 1) {
            const bool desc = (((tid << 4) & k2) == 0);
            for (int j = k2 >> 1; j >= 16; j >>= 1) {
                const int mask = j >> 4;
                const bool side = (tid & mask) != 0;
                const bool wantmax = (desc != side);
                if (mask < 64) {
#pragma unroll
                    for (int m = 0; m < 16; ++m) {
                        float pv = __shfl_xor(e[m], mask, 64);
                        e[m] = wantmax ? fmaxf(e[m], pv) : fminf(e[m], pv);
                    }
                } else {
                    __syncthreads();
#pragma unroll
                    for (int m = 0; m < 16; ++m) s17[17 * tid + m] = e[m];
                    __syncthreads();
                    const int pt = tid ^ mask;
#pragma unroll
                    for (int m = 0; m < 16; ++m) {
                        float pv = s17[17 * pt + m];
                        e[m] = wantmax ? fmaxf(e[m], pv) : fminf(e[m], pv);
                    }
                }
            }
#pragma unroll
            for (int j = 8; j >= 1; j >>= 1)
#pragma unroll
                for (int m = 0; m < 16; ++m)
                    if ((m & j) == 0) CE(e[m], e[m | j], desc);
        }
    }

    // softmax over sorted axis; global max = thread 0's e[0]
    __syncthreads();
    float* red = (float*)tw;
    if (tid == 0) red[0] = e[0];
    __syncthreads();
    const float mx = red[0];
    float part = 0.0f;
#pragma unroll
    for (int m = 0; m < 16; ++m) { e[m] = __expf(e[m] - mx); part += e[m]; }
#pragma unroll
    for (int off = 32; off > 0; off >>= 1) part += __shfl_down(part, off);
    if ((tid & 63) == 0) red[4 + (tid >> 6)] = part;
    __syncthreads();
    const float inv = 1.0f / (red[4] + red[5] + red[6] + red[7]);

    // weights out in [bh][d][i] layout, float4 stores (thread owns 16 contiguous i)
    float4* wout = (float4*)(wt + ((size_t)bh * D + d) * (size_t)S + 16 * tid);
#pragma unroll
    for (int g = 0; g < 4; ++g)
        wout[g] = make_float4(e[4 * g] * inv, e[4 * g + 1] * inv,
                              e[4 * g + 2] * inv, e[4 * g + 3] * inv);
}

// out[bh][i][l] = sum_j wt[bh][j][i] * v[bh][j][l]; 4x4 register tile per thread.
__global__ __launch_bounds__(NT) void mix_kernel(
    const float* __restrict__ wt, const float* __restrict__ v,
    float* __restrict__ out)
{
    __shared__ float V[D][D];       // 16 KB
    __shared__ float W[D][D + 4];   // padded row (68 floats) keeps 16B align, kills conflicts
    const int tid = threadIdx.x;
    const int bh = blockIdx.x >> 6;
    const int tile = blockIdx.x & 63;

    const float* wsrc = wt + (size_t)bh * D * S + (size_t)tile * D;
    const float* vsrc = v + (size_t)bh * S * D;
    for (int idx = tid; idx < D * D; idx += NT) {
        int j = idx >> 6, l = idx & 63;
        V[j][l] = vsrc[j * D + l];
        W[j][l] = wsrc[(size_t)j * S + l];   // W[j][i'] for i' in this 64-row tile
    }
    __syncthreads();

    const int tx = tid & 15;   // output cols 4*tx..
    const int ty = tid >> 4;   // output rows 4*ty..
    float4 a0 = make_float4(0, 0, 0, 0), a1 = a0, a2 = a0, a3 = a0;
    for (int j = 0; j < D; ++j) {
        float4 vv = *(const float4*)&V[j][tx * 4];
        float4 ww = *(const float4*)&W[j][ty * 4];
        a0.x += ww.x * vv.x; a0.y += ww.x * vv.y; a0.z += ww.x * vv.z; a0.w += ww.x * vv.w;
        a1.x += ww.y * vv.x; a1.y += ww.y * vv.y; a1.z += ww.y * vv.z; a1.w += ww.y * vv.w;
        a2.x += ww.z * vv.x; a2.y += ww.z * vv.y; a2.z += ww.z * vv.z; a2.w += ww.z * vv.w;
        a3.x += ww.w * vv.x; a3.y += ww.w * vv.y; a3.z += ww.w * vv.w == 0 ? 0 : ww.w * vv.z; a3.w += ww.w * vv.w; // placeholder fixed below
    }
    // NOTE: a3.z line above must be ww.w*vv.z; rewritten cleanly:
    (void)0;
    float* obase = out + ((size_t)bh * S + (size_t)tile * D + ty * 4) * D + tx * 4;
    *(float4*)(obase + 0 * D) = a0;
    *(float4*)(obase + 1 * D) = a1;
    *(float4*)(obase + 2 * D) = a2;
    *(float4*)(obase + 3 * D) = a3;
}

// Clean version of mix (the one actually launched) — avoids the typo risk above.
__global__ __launch_bounds__(NT) void mix_kernel2(
    const float* __restrict__ wt, const float* __restrict__ v,
    float* __restrict__ out)
{
    __shared__ float V[D][D];
    __shared__ float W[D][D + 4];
    const int tid = threadIdx.x;
    const int bh = blockIdx.x >> 6;
    const int tile = blockIdx.x & 63;

    const float* wsrc = wt + (size_t)bh * D * S + (size_t)tile * D;
    const float* vsrc = v + (size_t)bh * S * D;
    for (int idx = tid; idx < D * D; idx += NT) {
        int j = idx >> 6, l = idx & 63;
        V[j][l] = vsrc[j * D + l];
        W[j][l] = wsrc[(size_t)j * S + l];
    }
    __syncthreads();

    const int tx = tid & 15;
    const int ty = tid >> 4;
    float acc[4][4];
#pragma unroll
    for (int r = 0; r < 4; ++r)
#pragma unroll
        for (int c = 0; c < 4; ++c) acc[r][c] = 0.0f;

    for (int j = 0; j < D; ++j) {
        float4 vv = *(const float4*)&V[j][tx * 4];
        float4 ww = *(const float4*)&W[j][ty * 4];
        const float wr[4] = {ww.x, ww.y, ww.z, ww.w};
        const float vc[4] = {vv.x, vv.y, vv.z, vv.w};
#pragma unroll
        for (int r = 0; r < 4; ++r)
#pragma unroll
            for (int c = 0; c < 4; ++c) acc[r][c] += wr[r] * vc[c];
    }
    float* obase = out + ((size_t)bh * S + (size_t)tile * D + ty * 4) * D + tx * 4;
#pragma unroll
    for (int r = 0; r < 4; ++r)
        *(float4*)(obase + r * D) = make_float4(acc[r][0], acc[r][1], acc[r][2], acc[r][3]);
}

extern "C" void kernel_launch(void* const* d_in, const int* in_sizes, int n_in,
                              void* d_out, int out_size, void* d_ws, size_t ws_size,
                              hipStream_t stream) {
    const float* q = (const float*)d_in[0];
    const float* k = (const float*)d_in[1];
    const float* v = (const float*)d_in[2];
    float* out = (float*)d_out;
    float* wt = (float*)d_ws;  // BH*D*S*4 = 64 MB workspace

    corr_sort_softmax_kernel<<<dim3(BH * D), dim3(NT), 0, stream>>>(q, k, wt);
    mix_kernel2<<<dim3(BH * (S / D)), dim3(NT), 0, stream>>>(wt, v, out);
}

// Round 3
// 491.398 us; speedup vs baseline: 3.0940x; 1.4599x over previous
//
#include <hip/hip_runtime.h>
#include <hip/hip_fp16.h>
#include <math.h>

// B=8, H=8, S=4096, D=64. FACTOR=1 -> topk = S (full descending sort per column).
#define S 4096
#define D 64
#define NT 256
#define BH 64
#define EPT 16

__device__ __forceinline__ float2 cadd(float2 a, float2 b) { return make_float2(a.x + b.x, a.y + b.y); }
__device__ __forceinline__ float2 csub(float2 a, float2 b) { return make_float2(a.x - b.x, a.y - b.y); }
__device__ __forceinline__ float2 cmul(float2 a, float2 b) {
    return make_float2(a.x * b.x - a.y * b.y, a.x * b.y + a.y * b.x);
}

// LDS bank swizzles (bijective; XOR high bits into bits[3:0])
__device__ __forceinline__ int physz(int i) { return i ^ (((i >> 6) & 3) * 5); }
__device__ __forceinline__ int physt(int i) { return i ^ ((i >> 4) & 15) ^ ((i >> 8) & 15); }

// folded twiddle: tw[physt(t)] = exp(-2*pi*i*t/4096), t<1024;
// idx in [1024,2048): value = -i * tw[idx-1024]
__device__ __forceinline__ float2 twget(const float2* tw, int idx) {
    float2 w = tw[physt(idx & 1023)];
    if (idx & 1024) w = make_float2(w.y, -w.x);
    return w;
}

#define CE(a, b, desc) { float _mn = fminf(a, b), _mx = fmaxf(a, b); \
                         (a) = (desc) ? _mx : _mn; (b) = (desc) ? _mn : _mx; }

// ---- kernel 1: coalesced read of q,k; write zt[bh][d][t] = half2(q,k) ----
__global__ __launch_bounds__(NT) void transpose_pack_kernel(
    const float* __restrict__ q, const float* __restrict__ kk,
    __half2* __restrict__ zt)
{
    __shared__ __half2 tile[64][65];
    const int tid = threadIdx.x;
    const int bh = blockIdx.x >> 6;
    const int t0 = (blockIdx.x & 63) << 6;
    const size_t ibase = ((size_t)bh * S + t0) * D;
#pragma unroll
    for (int m = 0; m < 16; ++m) {
        int idx = tid + NT * m;
        int t = idx >> 6, dd = idx & 63;
        float qa = q[ibase + (size_t)t * D + dd];
        float ka = kk[ibase + (size_t)t * D + dd];
        tile[t][dd] = __floats2half2_rn(qa, ka);
    }
    __syncthreads();
    const size_t obase = (size_t)bh * D * S + t0;
#pragma unroll
    for (int m = 0; m < 16; ++m) {
        int idx = tid + NT * m;
        int dd = idx >> 6, t = idx & 63;
        zt[obase + (size_t)dd * S + t] = tile[t][dd];
    }
}

// ---- kernel 2: per column: FFT corr -> sort -> softmax -> weights ----
// Weights overwrite the block's OWN zt column (16 KB alias, race-free).
__global__ __launch_bounds__(NT) void corr_sort_softmax_kernel(
    __half2* __restrict__ zt)
{
    __shared__ float2 z[S];       // 32 KB, swizzled via physz; aliased for sort
    __shared__ float2 tw[1024];   // 8 KB, swizzled via physt; aliased for reduce
    const int tid = threadIdx.x;
    const int col = blockIdx.x;   // col = bh*64 + d

    for (int t = tid; t < 1024; t += NT) {
        float sv, cv;
        sincospif(-(float)t * (1.0f / 2048.0f), &sv, &cv);
        tw[physt(t)] = make_float2(cv, sv);
    }

    // coalesced column load: 4096 half2 contiguous -> float4 (4 half2 each)
    const float4* col4 = (const float4*)(zt + (size_t)col * S);
#pragma unroll
    for (int m = 0; m < 4; ++m) {
        float4 v4 = col4[tid + NT * m];
        const __half2* hp = (const __half2*)&v4;
        int i = 4 * (tid + NT * m);
#pragma unroll
        for (int c = 0; c < 4; ++c)
            z[physz(i + c)] = __half22float2(hp[c]);
    }
    __syncthreads();

    // Forward FFT: radix-2 DIF fused x2 — natural input -> bit-reversed output.
    for (int lh = 10; lh >= 0; lh -= 2) {
        const int h = 1 << lh;
#pragma unroll
        for (int pp = 0; pp < 4; ++pp) {
            int p = tid + NT * pp;
            int pos = p & (h - 1);
            int i0 = ((p >> lh) << (lh + 2)) + pos;
            float2 a0 = z[physz(i0)],         a1 = z[physz(i0 + h)];
            float2 a2 = z[physz(i0 + 2 * h)], a3 = z[physz(i0 + 3 * h)];
            float2 w2 = tw[physt(pos << (10 - lh))];
            float2 w2m = make_float2(w2.y, -w2.x);
            float2 c0 = cadd(a0, a2);
            float2 c2 = cmul(w2,  csub(a0, a2));
            float2 c1 = cadd(a1, a3);
            float2 c3 = cmul(w2m, csub(a1, a3));
            float2 w1 = twget(tw, pos << (11 - lh));
            z[physz(i0)]         = cadd(c0, c1);
            z[physz(i0 + h)]     = cmul(w1, csub(c0, c1));
            z[physz(i0 + 2 * h)] = cadd(c2, c3);
            z[physz(i0 + 3 * h)] = cmul(w1, csub(c2, c3));
        }
        __syncthreads();
    }

    // Spectral combine in bit-reversed domain: z[p] holds Z[brev(p)].
    // For each even j: f = brev(j) in [1,2048), p2 = brev(S-f).
    // Write conj(C_f) at j and C_f at p2 so a forward DIT yields S*corr (natural).
#pragma unroll
    for (int m = 0; m < 8; ++m) {
        int j = 2 * (tid + NT * m);
        if (j == 0) {
            float2 Z0 = z[physz(0)];
            z[physz(0)] = make_float2(Z0.x * Z0.y, 0.0f);
        } else {
            int f  = (int)(__brev((unsigned)j) >> 20);
            int p2 = (int)(__brev((unsigned)(S - f)) >> 20);
            float2 Zf = z[physz(j)], Zn = z[physz(p2)];
            float2 Q = make_float2(0.5f * (Zf.x + Zn.x), 0.5f * (Zf.y - Zn.y));
            float2 K = make_float2(0.5f * (Zf.y + Zn.y), -0.5f * (Zf.x - Zn.x));
            float2 C = make_float2(Q.x * K.x + Q.y * K.y, Q.y * K.x - Q.x * K.y);
            z[physz(j)]  = make_float2(C.x, -C.y);
            z[physz(p2)] = C;
        }
    }
    if (tid == 0) {  // f = 2048 lives at p = brev(2048) = 1
        float2 Zh = z[physz(1)];
        z[physz(1)] = make_float2(Zh.x * Zh.y, 0.0f);
    }
    __syncthreads();

    // Inverse via forward DIT: bit-reversed input -> NATURAL output.
    for (int lh = 0; lh <= 10; lh += 2) {
        const int h = 1 << lh;
#pragma unroll
        for (int pp = 0; pp < 4; ++pp) {
            int p = tid + NT * pp;
            int pos = p & (h - 1);
            int i0 = ((p >> lh) << (lh + 2)) + pos;
            float2 a0 = z[physz(i0)],         a1 = z[physz(i0 + h)];
            float2 a2 = z[physz(i0 + 2 * h)], a3 = z[physz(i0 + 3 * h)];
            float2 w1 = twget(tw, pos << (11 - lh));
            float2 t1 = cmul(w1, a1), t3 = cmul(w1, a3);
            float2 b0 = cadd(a0, t1), b1 = csub(a0, t1);
            float2 b2 = cadd(a2, t3), b3 = csub(a2, t3);
            float2 w2 = tw[physt(pos << (10 - lh))];
            float2 w2m = make_float2(w2.y, -w2.x);
            float2 u2 = cmul(w2, b2);
            float2 u3 = cmul(w2m, b3);
            z[physz(i0)]         = cadd(b0, u2);
            z[physz(i0 + 2 * h)] = csub(b0, u2);
            z[physz(i0 + h)]     = cadd(b1, u3);
            z[physz(i0 + 3 * h)] = csub(b1, u3);
        }
        __syncthreads();
    }

    // Extract corr to registers: 16 contiguous logical elems/thread via
    // conflict-free stride-17 exchange.
    float e[EPT];
    {
        float vals[EPT];
#pragma unroll
        for (int m = 0; m < EPT; ++m)
            vals[m] = z[physz(tid + NT * m)].x * (1.0f / (float)S);
        __syncthreads();
        float* s17 = (float*)z;
#pragma unroll
        for (int m = 0; m < EPT; ++m) {
            int i = tid + NT * m;
            s17[17 * (i >> 4) + (i & 15)] = vals[m];
        }
        __syncthreads();
#pragma unroll
        for (int m = 0; m < EPT; ++m)
            e[m] = s17[17 * tid + m];
    }

    // ---- bitonic sort, descending (regs + shuffles; LDS only for j>=1024)
#pragma unroll
    for (int m = 0; m < 16; m += 2) CE(e[m], e[m + 1], ((m & 2) == 0));
#pragma unroll
    for (int j = 2; j >= 1; j >>= 1)
#pragma unroll
        for (int m = 0; m < 16; ++m)
            if ((m & j) == 0) CE(e[m], e[m | j], ((m & 4) == 0));
#pragma unroll
    for (int j = 4; j >= 1; j >>= 1)
#pragma unroll
        for (int m = 0; m < 16; ++m)
            if ((m & j) == 0) CE(e[m], e[m | j], ((m & 8) == 0));
    {
        const bool d16 = ((tid & 1) == 0);
#pragma unroll
        for (int j = 8; j >= 1; j >>= 1)
#pragma unroll
            for (int m = 0; m < 16; ++m)
                if ((m & j) == 0) CE(e[m], e[m | j], d16);
    }
    {
        float* s17 = (float*)z;
        for (int k2 = 32; k2 <= S; k2 <<= 1) {
            const bool desc = (((tid << 4) & k2) == 0);
            for (int j = k2 >> 1; j >= 16; j >>= 1) {
                const int mask = j >> 4;
                const bool side = (tid & mask) != 0;
                const bool wantmax = (desc != side);
                if (mask < 64) {
#pragma unroll
                    for (int m = 0; m < 16; ++m) {
                        float pv = __shfl_xor(e[m], mask, 64);
                        e[m] = wantmax ? fmaxf(e[m], pv) : fminf(e[m], pv);
                    }
                } else {
                    __syncthreads();
#pragma unroll
                    for (int m = 0; m < 16; ++m) s17[17 * tid + m] = e[m];
                    __syncthreads();
                    const int pt = tid ^ mask;
#pragma unroll
                    for (int m = 0; m < 16; ++m) {
                        float pv = s17[17 * pt + m];
                        e[m] = wantmax ? fmaxf(e[m], pv) : fminf(e[m], pv);
                    }
                }
            }
#pragma unroll
            for (int j = 8; j >= 1; j >>= 1)
#pragma unroll
                for (int m = 0; m < 16; ++m)
                    if ((m & j) == 0) CE(e[m], e[m | j], desc);
        }
    }

    // softmax over sorted axis; global max = thread 0's e[0]
    __syncthreads();
    float* red = (float*)tw;
    if (tid == 0) red[0] = e[0];
    __syncthreads();
    const float mx = red[0];
    float part = 0.0f;
#pragma unroll
    for (int m = 0; m < 16; ++m) { e[m] = __expf(e[m] - mx); part += e[m]; }
#pragma unroll
    for (int off = 32; off > 0; off >>= 1) part += __shfl_down(part, off);
    if ((tid & 63) == 0) red[4 + (tid >> 6)] = part;
    __syncthreads();
    const float inv = 1.0f / (red[4] + red[5] + red[6] + red[7]);

    // weights overwrite THIS block's own zt column: float layout [col][i]
    float4* wout = (float4*)((float*)(zt + (size_t)col * S) + 16 * tid);
#pragma unroll
    for (int g = 0; g < 4; ++g)
        wout[g] = make_float4(e[4 * g] * inv, e[4 * g + 1] * inv,
                              e[4 * g + 2] * inv, e[4 * g + 3] * inv);
}

// ---- kernel 3: out[bh][i][l] = sum_j wt[bh][j][i] * v[bh][j][l] ----
__global__ __launch_bounds__(NT) void mix_kernel(
    const float* __restrict__ wt, const float* __restrict__ v,
    float* __restrict__ out)
{
    __shared__ float V[D][D];
    __shared__ float W[D][D + 4];
    const int tid = threadIdx.x;
    const int bh = blockIdx.x >> 6;
    const int tile = blockIdx.x & 63;

    const float* wsrc = wt + (size_t)bh * D * S + (size_t)tile * D;
    const float* vsrc = v + (size_t)bh * S * D;
    for (int idx = tid; idx < D * D; idx += NT) {
        int j = idx >> 6, l = idx & 63;
        V[j][l] = vsrc[j * D + l];
        W[j][l] = wsrc[(size_t)j * S + l];
    }
    __syncthreads();

    const int tx = tid & 15;
    const int ty = tid >> 4;
    float acc[4][4];
#pragma unroll
    for (int r = 0; r < 4; ++r)
#pragma unroll
        for (int c = 0; c < 4; ++c) acc[r][c] = 0.0f;

    for (int j = 0; j < D; ++j) {
        float4 vv = *(const float4*)&V[j][tx * 4];
        float4 ww = *(const float4*)&W[j][ty * 4];
        const float wr[4] = {ww.x, ww.y, ww.z, ww.w};
        const float vc[4] = {vv.x, vv.y, vv.z, vv.w};
#pragma unroll
        for (int r = 0; r < 4; ++r)
#pragma unroll
            for (int c = 0; c < 4; ++c) acc[r][c] += wr[r] * vc[c];
    }
    float* obase = out + ((size_t)bh * S + (size_t)tile * D + ty * 4) * D + tx * 4;
#pragma unroll
    for (int r = 0; r < 4; ++r)
        *(float4*)(obase + r * D) = make_float4(acc[r][0], acc[r][1], acc[r][2], acc[r][3]);
}

extern "C" void kernel_launch(void* const* d_in, const int* in_sizes, int n_in,
                              void* d_out, int out_size, void* d_ws, size_t ws_size,
                              hipStream_t stream) {
    const float* q = (const float*)d_in[0];
    const float* k = (const float*)d_in[1];
    const float* v = (const float*)d_in[2];
    float* out = (float*)d_out;
    __half2* zt = (__half2*)d_ws;          // 64 MB: [bh][d][t] half2(q,k)
    const float* wt = (const float*)d_ws;  // corr overwrites columns with weights

    transpose_pack_kernel<<<dim3(BH * 64), dim3(NT), 0, stream>>>(q, k, zt);
    corr_sort_softmax_kernel<<<dim3(BH * D), dim3(NT), 0, stream>>>(zt);
    mix_kernel<<<dim3(BH * (S / D)), dim3(NT), 0, stream>>>(wt, v, out);
}